// Round 1
// baseline (95.854 us; speedup 1.0000x reference)
//
#include <hip/hip_runtime.h>
#include <math.h>

#define HID  128
#define NPOS 80
#define XS   136   // padded LDS X stride (bf16 elems)

typedef float f4 __attribute__((ext_vector_type(4)));
typedef float f2 __attribute__((ext_vector_type(2)));
typedef unsigned int u32;
typedef u32 u32x4 __attribute__((ext_vector_type(4)));
typedef __attribute__((ext_vector_type(8))) short bf16x8;
typedef __attribute__((ext_vector_type(4))) float f32x4;

__device__ __forceinline__ float elu(float x) { return x > 0.f ? x : (expf(x) - 1.f); }
__device__ __forceinline__ unsigned short f2bf(float x) {
    u32 u = __float_as_uint(x);
    return (unsigned short)((u + 0x7fffu + ((u >> 16) & 1u)) >> 16);
}
__device__ __forceinline__ float bf2f(unsigned short h) { return __uint_as_float(((u32)h) << 16); }

// ---- fp8 e4m3fn: software RNE encode (prep-side) ----
__device__ __forceinline__ u32 f2e4m3(float x) {
    u32 u = __float_as_uint(x);
    u32 sign = (u >> 31) << 7;
    float a = fabsf(x);
    if (a >= 448.f) return sign | 0x7e;
    int e = (int)((u >> 23) & 0xff) - 127;
    if (e < -6) {
        int q = (int)rintf(a * 512.0f);
        if (q >= 8) return sign | 0x08;
        return sign | (u32)q;
    }
    u32 sig = (u & 0x7fffffu) | 0x800000u;
    u32 rs = sig + 0x7ffffu + ((sig >> 20) & 1u);
    if (rs >= 0x1000000u) { e += 1; rs >>= 1; }
    u32 m3 = (rs >> 20) & 7u;
    u32 enc = ((u32)(e + 7) << 3) | m3;
    if (enc >= 0x7fu) return sign | 0x7e;
    return sign | enc;
}

#if defined(__has_builtin)
#if __has_builtin(__builtin_amdgcn_cvt_pk_f32_fp8)
#define HW_FP8 1
#endif
#endif

#ifdef HW_FP8
// packed decode+accumulate: 2 cvt_pk + 2 v_pk_add_f32 per u32 (was 2 cvt + 4 scalar adds)
__device__ __forceinline__ void dec4_acc2(u32 v, f2& a0, f2& a1) {
    a0 += __builtin_amdgcn_cvt_pk_f32_fp8((int)v, false);
    a1 += __builtin_amdgcn_cvt_pk_f32_fp8((int)v, true);
}
#else
__device__ __forceinline__ float dec1(u32 b) {
    int em = (int)(b & 0x7fu);
    int isn = (em >= 8) ? 1 : 0;
    int frac = (em & 7) | (isn << 3);
    int e2 = isn ? (em >> 3) : 1;
    float f = ldexpf((float)frac, e2 - 10);
    return (b & 0x80u) ? -f : f;
}
__device__ __forceinline__ void dec4_acc2(u32 v, f2& a0, f2& a1) {
    a0.x += dec1(v & 0xff);         a0.y += dec1((v >> 8) & 0xff);
    a1.x += dec1((v >> 16) & 0xff); a1.y += dec1(v >> 24);
}
#endif

// ---- prep: W1 -> fp8(x64) [2560 blocks]; W2/3/4 -> B-frag order (L,w8,kt,lane) [24 blocks] ----
#define W1_BLOCKS 2560
#define TR_BLOCKS 24
__global__ __launch_bounds__(256) void prep(
    const float* __restrict__ W1, const float* __restrict__ W2,
    const float* __restrict__ W3, const float* __restrict__ W4,
    u32* __restrict__ W1f8,
    unsigned short* __restrict__ WtH, unsigned short* __restrict__ WtL)
{
    int b = blockIdx.x;
    if (b < W1_BLOCKS) {
        int i = b * 256 + threadIdx.x;
        f4 f = ((const f4*)W1)[i];
        u32 pk = f2e4m3(f.x * 64.f)
               | (f2e4m3(f.y * 64.f) << 8)
               | (f2e4m3(f.z * 64.f) << 16)
               | (f2e4m3(f.w * 64.f) << 24);
        W1f8[i] = pk;
    } else {
        int t = (b - W1_BLOCKS) * 256 + threadIdx.x;   // 0..6143 = (L, w8, kt, lane)
        int lane = t & 63;
        int q = t >> 6;
        int kt = q & 3;  q >>= 2;
        int w  = q & 7;
        int L  = q >> 3;
        const float* W = (L == 0) ? W2 : (L == 1) ? W3 : W4;
        const int n    = w * 16 + (lane & 15);
        const int quad = lane >> 4;
        unsigned short hs[8], ls[8];
        #pragma unroll
        for (int j = 0; j < 8; ++j) {
            const int k = kt * 32 + quad * 8 + j;
            float v = W[k * HID + n];
            hs[j] = f2bf(v);
            ls[j] = f2bf(v - bf2f(hs[j]));
        }
        *(ushort4*)&WtH[t * 8]     = make_ushort4(hs[0], hs[1], hs[2], hs[3]);
        *(ushort4*)&WtH[t * 8 + 4] = make_ushort4(hs[4], hs[5], hs[6], hs[7]);
        *(ushort4*)&WtL[t * 8]     = make_ushort4(ls[0], ls[1], ls[2], ls[3]);
        *(ushort4*)&WtL[t * 8 + 4] = make_ushort4(ls[4], ls[5], ls[6], ls[7]);
    }
}

// ---- fused: fp8 gather (2 full rows/wave, butterfly reduce) + MFMA dense ----
__global__ __launch_bounds__(512, 4) void main_k(
    const int* __restrict__ msg, const unsigned char* __restrict__ W1f8,
    const float* __restrict__ b1,
    const unsigned short* __restrict__ WtH, const unsigned short* __restrict__ WtL,
    const float* __restrict__ b2, const float* __restrict__ b3,
    const float* __restrict__ b4, float* __restrict__ out)
{
    const int tid = threadIdx.x, lane = tid & 63, w = tid >> 6;   // w: 0..7
    const int quad = lane >> 4, l15 = lane & 15;
    const int r0 = blockIdx.x * 16;

    __shared__ int smsg[16 * NPOS];              // 5 KB
    __shared__ unsigned short Xh[16 * XS];       // 4.25 KB
    __shared__ unsigned short Xl[16 * XS];       // 4.25 KB   (no more 32 KB P buffer)

    for (int k = tid; k < 16 * NPOS; k += 512)
        smsg[k] = __builtin_nontemporal_load(&msg[r0 * NPOS + k]);
    __syncthreads();

    // ---- gather: wave w owns rows {2w, 2w+1}; position quartering is INTRA-wave ----
    {
        const int half = lane >> 5;                 // 0,1 -> which of the wave's 2 rows
        const int row  = (w << 1) | half;           // block-local row 0..15
        const int l5   = lane & 31;
        const int pg   = l5 >> 3;                   // position group 0..3 (bits 3..4 of lane)
        const int colb = (l5 & 7) << 4;             // byte (=col) offset in 128B row
        const int* mr = &smsg[row * NPOS];
        f2 A[8] = {};                               // 16 f32 partial sums, packed
        #pragma unroll
        for (int h = 0; h < 2; ++h) {
            int c[10];
            #pragma unroll
            for (int u = 0; u < 10; ++u) c[u] = mr[pg + ((h * 10 + u) << 2)];
            u32x4 v[10];
            #pragma unroll
            for (int u = 0; u < 10; ++u) {
                const int pos = pg + ((h * 10 + u) << 2);
                v[u] = *(const u32x4*)(W1f8 + ((pos << 15) + (c[u] << 7) + colb));
            }
            #pragma unroll
            for (int u = 0; u < 10; ++u) {
                dec4_acc2(v[u].x, A[0], A[1]);
                dec4_acc2(v[u].y, A[2], A[3]);
                dec4_acc2(v[u].z, A[4], A[5]);
                dec4_acc2(v[u].w, A[6], A[7]);
            }
        }
        // butterfly over the 4 position groups (lanes differing in bits 3,4; bit 5 = row untouched)
        #pragma unroll
        for (int j = 0; j < 8; ++j) {
            A[j].x += __shfl_xor(A[j].x, 8, 64);
            A[j].y += __shfl_xor(A[j].y, 8, 64);
        }
        #pragma unroll
        for (int j = 0; j < 8; ++j) {
            A[j].x += __shfl_xor(A[j].x, 16, 64);
            A[j].y += __shfl_xor(A[j].y, 16, 64);
        }
        // every lane now holds the full 16-col sum; the 4 pg-duplicates split the epilogue.
        // static-index select (rule #20: no runtime-indexed ext_vector arrays)
        f2 s0 = A[0], s1 = A[1];
        if (pg == 1)      { s0 = A[2]; s1 = A[3]; }
        else if (pg == 2) { s0 = A[4]; s1 = A[5]; }
        else if (pg == 3) { s0 = A[6]; s1 = A[7]; }
        const int colq = colb + (pg << 2);
        const f4 bb = *(const f4*)&b1[colq];
        const float y0 = elu(s0.x * 0.015625f + bb.x);
        const float y1 = elu(s0.y * 0.015625f + bb.y);
        const float y2 = elu(s1.x * 0.015625f + bb.z);
        const float y3 = elu(s1.y * 0.015625f + bb.w);
        const unsigned short h0 = f2bf(y0), h1 = f2bf(y1), h2 = f2bf(y2), h3 = f2bf(y3);
        *(ushort4*)&Xh[row * XS + colq] = make_ushort4(h0, h1, h2, h3);
        *(ushort4*)&Xl[row * XS + colq] = make_ushort4(
            f2bf(y0 - bf2f(h0)), f2bf(y1 - bf2f(h1)),
            f2bf(y2 - bf2f(h2)), f2bf(y3 - bf2f(h3)));
    }
    __syncthreads();

    // ---- dense: MFMA 16x16x32, 3-pass hi/lo; wave w owns n-columns [16w,16w+16) ----
    const float* bs[3] = { b2, b3, b4 };
    #pragma unroll 1
    for (int L = 0; L < 3; ++L) {
        bf16x8 Ah[4], Al[4];
        #pragma unroll
        for (int kt = 0; kt < 4; ++kt) {
            const int off = l15 * XS + kt * 32 + quad * 8;
            Ah[kt] = *(const bf16x8*)&Xh[off];
            Al[kt] = *(const bf16x8*)&Xl[off];
        }
        const unsigned short* WH = WtH + L * 16384;
        const unsigned short* WL = WtL + L * 16384;
        f32x4 acc = {0, 0, 0, 0};
        #pragma unroll
        for (int kt = 0; kt < 4; ++kt) {
            const int boff = (w * 4 + kt) * 512 + lane * 8;      // contiguous 1KB/wave
            bf16x8 Bh = *(const bf16x8*)&WH[boff];
            bf16x8 Bl = *(const bf16x8*)&WL[boff];
            acc = __builtin_amdgcn_mfma_f32_16x16x32_bf16(Ah[kt], Bh, acc, 0, 0, 0);
            acc = __builtin_amdgcn_mfma_f32_16x16x32_bf16(Ah[kt], Bl, acc, 0, 0, 0);
            acc = __builtin_amdgcn_mfma_f32_16x16x32_bf16(Al[kt], Bh, acc, 0, 0, 0);
        }
        __syncthreads();   // A-frag reads retired before X overwrite

        const int n = w * 16 + l15;
        const float bias = bs[L][n];
        #pragma unroll
        for (int r = 0; r < 4; ++r) {
            const int mm = quad * 4 + r;              // C layout: col=l15, row=quad*4+reg
            const float y = elu(acc[r] + bias);
            if (L < 2) {
                unsigned short hi = f2bf(y);
                Xh[mm * XS + n] = hi;
                Xl[mm * XS + n] = f2bf(y - bf2f(hi));
            } else {
                __builtin_nontemporal_store(y, &out[(r0 + mm) * HID + n]);
            }
        }
        if (L < 2) __syncthreads();
    }
}

extern "C" void kernel_launch(void* const* d_in, const int* in_sizes, int n_in,
                              void* d_out, int out_size, void* d_ws, size_t ws_size,
                              hipStream_t stream) {
    const int*   msg = (const int*)  d_in[0];
    const float* W1  = (const float*)d_in[1];
    const float* b1  = (const float*)d_in[2];
    const float* W2  = (const float*)d_in[3];
    const float* b2  = (const float*)d_in[4];
    const float* W3  = (const float*)d_in[5];
    const float* b3  = (const float*)d_in[6];
    const float* W4  = (const float*)d_in[7];
    const float* b4  = (const float*)d_in[8];
    float* out = (float*)d_out;

    // ws layout: W1f8 (2,621,440 bytes) | WtH (49,152 us) | WtL (49,152 us)
    unsigned char*  W1f8 = (unsigned char*)d_ws;
    unsigned short* WtH  = (unsigned short*)(W1f8 + 2621440);
    unsigned short* WtL  = WtH + 49152;

    prep  <<<dim3(W1_BLOCKS + TR_BLOCKS), dim3(256), 0, stream>>>(W1, W2, W3, W4,
                                                                  (u32*)W1f8, WtH, WtL);
    main_k<<<dim3(512),                   dim3(512), 0, stream>>>(msg, W1f8, b1, WtH, WtL,
                                                                  b2, b3, b4, out);
}